// Round 14
// baseline (253.958 us; speedup 1.0000x reference)
//
#include <hip/hip_runtime.h>
#include <hip/hip_bf16.h>

#define D_IN  768
#define D_E   256
#define M_TOT 512      // B*S
#define E_TOT 100000

typedef __attribute__((ext_vector_type(4))) float f32x4;
typedef __attribute__((ext_vector_type(8))) short bf16x8;

__device__ __forceinline__ unsigned short bf16bits(float f) {
    union { __hip_bfloat16 h; unsigned short u; } c;
    c.h = __float2bfloat16(f);
    return c.u;
}

__device__ __forceinline__ void gload_lds16(const void* g, void* l) {
    __builtin_amdgcn_global_load_lds(
        (const __attribute__((address_space(1))) void*)g,
        (__attribute__((address_space(3))) void*)l, 16, 0, 0);
}

// ---------------------------------------------------------------------------
// Fused prep+proj (unchanged — at BW floor):
//   blocks [0,64):    proj  qb[m][e] = bf16(tanh(x@W^T+b)/||row||)
//   blocks [64,1627): prep  eb[n][k] = bf16(en[n][k]/||en[n]||)
// ---------------------------------------------------------------------------
#define PROJ_BLOCKS 64
#define PREP_BLOCKS 1563
#define PP_GRID (PROJ_BLOCKS + PREP_BLOCKS)
#define PTM 8
#define PBK 64
#define PROUNDS (D_IN / PBK)             // 12

__global__ __launch_bounds__(512) void fused_pp(
    const float* __restrict__ x, const float* __restrict__ W,
    const float* __restrict__ b, const float* __restrict__ en,
    unsigned short* __restrict__ qb, unsigned short* __restrict__ eb)
{
    __shared__ float ws[D_E * (PBK + 1)];
    __shared__ float xs[PTM][PBK];
    __shared__ float red[PTM][4];
    __shared__ float qiv[PTM];

    const int t   = threadIdx.x;
    const int bid = blockIdx.x;

    if (bid >= PROJ_BLOCKS) {
        const int lane = t & 63;
        const int gw   = (bid - PROJ_BLOCKS) * 8 + (t >> 6);
        #pragma unroll 2
        for (int i = 0; i < 8; ++i) {
            const int row = gw * 8 + i;
            if (row >= E_TOT) break;
            const float4 v = *reinterpret_cast<const float4*>(
                en + (size_t)row * D_E + lane * 4);
            float s = v.x*v.x + v.y*v.y + v.z*v.z + v.w*v.w;
            #pragma unroll
            for (int off = 1; off < 64; off <<= 1) s += __shfl_xor(s, off, 64);
            const float sc = 1.0f / fmaxf(sqrtf(s), 1e-8f);
            union { unsigned short u[4]; uint2 d; } o;
            o.u[0] = bf16bits(v.x * sc); o.u[1] = bf16bits(v.y * sc);
            o.u[2] = bf16bits(v.z * sc); o.u[3] = bf16bits(v.w * sc);
            *reinterpret_cast<uint2*>(eb + (size_t)row * D_E + lane * 4) = o.d;
        }
        return;
    }

    const int m0   = bid * PTM;
    const int e    = t & 255;
    const int half = t >> 8;
    const int c4   = t & 15;
    const int rr   = t >> 4;

    float4 wreg[8];
    float  xreg = 0.f;
    float  acc[4] = {0.f, 0.f, 0.f, 0.f};

    #pragma unroll
    for (int i = 0; i < 8; ++i)
        wreg[i] = *reinterpret_cast<const float4*>(
            &W[(size_t)(i * 32 + rr) * D_IN + c4 * 4]);
    xreg = x[(size_t)(m0 + (t >> 6)) * D_IN + (t & 63)];

    for (int rd = 0; rd < PROUNDS; ++rd) {
        #pragma unroll
        for (int i = 0; i < 8; ++i) {
            float* dst = &ws[(i * 32 + rr) * (PBK + 1) + c4 * 4];
            dst[0] = wreg[i].x; dst[1] = wreg[i].y;
            dst[2] = wreg[i].z; dst[3] = wreg[i].w;
        }
        xs[t >> 6][t & 63] = xreg;
        __syncthreads();
        if (rd + 1 < PROUNDS) {
            const int k0 = (rd + 1) * PBK;
            #pragma unroll
            for (int i = 0; i < 8; ++i)
                wreg[i] = *reinterpret_cast<const float4*>(
                    &W[(size_t)(i * 32 + rr) * D_IN + k0 + c4 * 4]);
            xreg = x[(size_t)(m0 + (t >> 6)) * D_IN + k0 + (t & 63)];
        }
        #pragma unroll
        for (int k = 0; k < PBK; ++k) {
            const float wv = ws[e * (PBK + 1) + k];
            #pragma unroll
            for (int j = 0; j < 4; ++j)
                acc[j] = fmaf(xs[half * 4 + j][k], wv, acc[j]);
        }
        __syncthreads();
    }

    const float bias = b[e];
    const int wv4 = (t >> 6) & 3;
    const int lane = t & 63;
    float q[4];
    #pragma unroll
    for (int j = 0; j < 4; ++j) {
        q[j] = tanhf(acc[j] + bias);
        float s = q[j] * q[j];
        #pragma unroll
        for (int off = 1; off < 64; off <<= 1) s += __shfl_xor(s, off, 64);
        if (lane == 0) red[half * 4 + j][wv4] = s;
    }
    __syncthreads();
    if (t < PTM) {
        const float s = red[t][0] + red[t][1] + red[t][2] + red[t][3];
        qiv[t] = 1.0f / fmaxf(sqrtf(s), 1e-8f);
    }
    __syncthreads();
    #pragma unroll
    for (int j = 0; j < 4; ++j)
        qb[(size_t)(m0 + half * 4 + j) * D_E + e] =
            bf16bits(q[j] * qiv[half * 4 + j]);
}

// ---------------------------------------------------------------------------
// Kernel 2 (v14): LDS-sourced (remat-proof) + 4 waves/SIMD + counted-vmcnt
// 3-buffer pipeline.
//   Block 512 thr (8 waves = 2 wm x 4 wn of 32m x 32n), tile = 64m x 128n.
//   K split into 4 pieces of 64 (16 KB each), 3 rotating LDS bufs staged
//   2 steps ahead.  qs (64x256, 32 KB) staged once -> q panel in 64 VGPRs
//   (ds_read source: compiler cannot rematerialize).  LDS = 80 KB ->
//   exactly 2 blocks/CU -> 16 waves/CU = 4/SIMD.
//   vmcnt ladder (derived): prologue 2, steady per tile [6,6,2,2], final 0.
//   Stores fire-and-forget, >=3 steps to drain, never forced early.
//   Grid 488 = 61 ngrps x 8 m-blocks, XCD-chunked (8 m-blocks sharing an
//   eb slice -> same XCD's L2).
// ---------------------------------------------------------------------------
#define TPB 13                          // n-tiles (128 cols) per block
#define NP (TPB * 4)                    // 52 k-pieces
#define NGRPS 61                        // 61*13*128 = 101504 >= 100000
#define SIM_GRID (NGRPS * 8)            // 488

__device__ __forceinline__ void stage_piece(
    const unsigned short* __restrict__ eb, int nbase, int g,
    unsigned short* dst, int t)
{
    const int kk  = g & 3;
    const int nt0 = nbase + (g >> 2) * 128;
    #pragma unroll
    for (int i = 0; i < 2; ++i) {
        const int c  = i * 512 + t;       // 16B-chunk index (0..1023)
        const int n  = c >> 3;            // 0..127 entity row
        const int c8 = c & 7;             // chunk within 128B row-piece
        int rg = nt0 + n;
        if (rg >= E_TOT) rg = E_TOT - 1;  // clamp: uniform 2 ops always
        gload_lds16(eb + (size_t)rg * D_E + kk * 64 + ((c8 ^ (n & 7)) << 3),
                    (void*)&dst[(size_t)c << 3]);
    }
}

__global__ __launch_bounds__(512, 4) void sim_kernel(
    const unsigned short* __restrict__ eb, const unsigned short* __restrict__ qb,
    float* __restrict__ out)
{
    __shared__ unsigned short qs[64 * D_E];       // 32 KB
    __shared__ unsigned short es[3][128 * 64];    // 3 x 16 KB

    const int t    = threadIdx.x;
    const int lane = t & 63;
    const int w    = t >> 6;        // 0..7
    const int l15  = lane & 15;
    const int lk   = lane >> 4;     // 0..3
    const int wm   = (w >> 2) * 32; // 0,32
    const int wn   = (w & 3) * 32;  // 0,32,64,96

    // XCD-chunked bijective swizzle (488 = 8*61): 8 consecutive vbids =
    // the 8 m-blocks of one ngrp -> same XCD.
    const int vbid = (blockIdx.x & 7) * NGRPS + (blockIdx.x >> 3);
    const int mg    = vbid & 7;
    const int ngrp  = vbid >> 3;          // 0..60
    const int m0    = mg * 64;
    const int nbase = ngrp * (TPB * 128); // ngrp * 1664

    // ---- prologue: stage qs (4 ops/thr) + pieces 0,1 (2+2 ops) ----
    #pragma unroll
    for (int i = 0; i < 4; ++i) {
        const int c   = i * 512 + t;      // 0..2047
        const int row = c >> 5;           // 0..63
        const int c16 = c & 31;
        gload_lds16(qb + (size_t)(m0 + row) * D_E + ((c16 ^ (row & 7)) << 3),
                    (void*)&qs[(size_t)c << 3]);
    }
    stage_piece(eb, nbase, 0, &es[0][0], t);
    stage_piece(eb, nbase, 1, &es[1][0], t);

    // qs retired (p0,p1 still in flight) -> load q panel into registers
    asm volatile("s_waitcnt vmcnt(4)" ::: "memory");
    __builtin_amdgcn_sched_barrier(0);
    __builtin_amdgcn_s_barrier();
    __builtin_amdgcn_sched_barrier(0);

    const char* qsb = reinterpret_cast<const char*>(qs);
    bf16x8 qf[2][8];
    #pragma unroll
    for (int mf = 0; mf < 2; ++mf) {
        const int rq = wm + mf * 16 + l15;
        #pragma unroll
        for (int ks = 0; ks < 8; ++ks) {
            const int cb = (ks * 64 + lk * 16) ^ ((rq & 7) << 4);
            qf[mf][ks] = *reinterpret_cast<const bf16x8*>(qsb + rq * 512 + cb);
        }
    }

    f32x4 acc[2][2];

    #pragma unroll 1
    for (int g = 0; g < NP; ++g) {
        // ---- counted vmcnt ladder (never drains stores early) ----
        if (g == NP - 1)                asm volatile("s_waitcnt vmcnt(0)" ::: "memory");
        else if (g >= 4 && (g & 3) < 2) asm volatile("s_waitcnt vmcnt(6)" ::: "memory");
        else                            asm volatile("s_waitcnt vmcnt(2)" ::: "memory");
        __builtin_amdgcn_sched_barrier(0);
        __builtin_amdgcn_s_barrier();
        __builtin_amdgcn_sched_barrier(0);

        // stage piece g+2 into the buffer being vacated
        if (g + 2 < NP)
            stage_piece(eb, nbase, g + 2, &es[(g + 2) % 3][0], t);

        if ((g & 3) == 0) {
            #pragma unroll
            for (int mf = 0; mf < 2; ++mf)
                #pragma unroll
                for (int nf = 0; nf < 2; ++nf)
                    acc[mf][nf] = (f32x4){0.f, 0.f, 0.f, 0.f};
        }

        const char* esb = reinterpret_cast<const char*>(&es[g % 3][0]);

        bf16x8 ef[2][2];
        #pragma unroll
        for (int nf = 0; nf < 2; ++nf) {
            const int n = wn + nf * 16 + l15;
            #pragma unroll
            for (int s = 0; s < 2; ++s) {
                const int cb = (s * 64 + lk * 16) ^ ((n & 7) << 4);
                ef[nf][s] = *reinterpret_cast<const bf16x8*>(esb + n * 128 + cb);
            }
        }

        __builtin_amdgcn_s_setprio(1);
        #pragma unroll
        for (int s = 0; s < 2; ++s) {
            const int ksg = (g & 3) * 2 + s;
            #pragma unroll
            for (int mf = 0; mf < 2; ++mf) {
                acc[mf][0] = __builtin_amdgcn_mfma_f32_16x16x32_bf16(
                    ef[0][s], qf[mf][ksg], acc[mf][0], 0, 0, 0);
                acc[mf][1] = __builtin_amdgcn_mfma_f32_16x16x32_bf16(
                    ef[1][s], qf[mf][ksg], acc[mf][1], 0, 0, 0);
            }
        }
        __builtin_amdgcn_s_setprio(0);

        // end of tile: fire-and-forget stores (>=3 steps to drain)
        if ((g & 3) == 3) {
            const int nt0 = nbase + (g >> 2) * 128;
            #pragma unroll
            for (int mf = 0; mf < 2; ++mf) {
                const int m = m0 + wm + mf * 16 + l15;
                #pragma unroll
                for (int nf = 0; nf < 2; ++nf) {
                    const int n = nt0 + wn + nf * 16 + lk * 4;
                    if (n < E_TOT)   // E%4==0 -> whole f32x4 valid
                        *reinterpret_cast<f32x4*>(
                            &out[(size_t)m * E_TOT + n]) = acc[mf][nf];
                }
            }
        }
    }
}

// ---------------------------------------------------------------------------
extern "C" void kernel_launch(void* const* d_in, const int* in_sizes, int n_in,
                              void* d_out, int out_size, void* d_ws, size_t ws_size,
                              hipStream_t stream) {
    const float* x  = (const float*)d_in[0];   // [4,128,768]
    const float* W  = (const float*)d_in[1];   // [256,768]
    const float* b  = (const float*)d_in[2];   // [256]
    const float* en = (const float*)d_in[3];   // [100000,256]
    float* out = (float*)d_out;                // [512,100000]

    unsigned short* qb = (unsigned short*)d_ws;                 // 256 KB
    unsigned short* eb = (unsigned short*)((char*)d_ws + (size_t)M_TOT * D_E * 2);

    fused_pp<<<PP_GRID, 512, 0, stream>>>(x, W, b, en, qb, eb); // 1627 blocks
    sim_kernel<<<SIM_GRID, 512, 0, stream>>>(eb, qb, out);      // 488 blocks
}

// Round 15
// 150.692 us; speedup vs baseline: 1.6853x; 1.6853x over previous
//
#include <hip/hip_runtime.h>
#include <hip/hip_bf16.h>

#define D_IN  768
#define D_E   256
#define M_TOT 512      // B*S
#define E_TOT 100000

typedef __attribute__((ext_vector_type(4))) float f32x4;
typedef __attribute__((ext_vector_type(8))) short bf16x8;

__device__ __forceinline__ unsigned short bf16bits(float f) {
    union { __hip_bfloat16 h; unsigned short u; } c;
    c.h = __float2bfloat16(f);
    return c.u;
}

__device__ __forceinline__ void gload_lds16(const void* g, void* l) {
    __builtin_amdgcn_global_load_lds(
        (const __attribute__((address_space(1))) void*)g,
        (__attribute__((address_space(3))) void*)l, 16, 0, 0);
}

// ---------------------------------------------------------------------------
// Fused prep+proj (unchanged — at BW floor):
//   blocks [0,64):    proj  qb[m][e] = bf16(tanh(x@W^T+b)/||row||)
//   blocks [64,1627): prep  eb[n][k] = bf16(en[n][k]/||en[n]||)
// ---------------------------------------------------------------------------
#define PROJ_BLOCKS 64
#define PREP_BLOCKS 1563
#define PP_GRID (PROJ_BLOCKS + PREP_BLOCKS)
#define PTM 8
#define PBK 64
#define PROUNDS (D_IN / PBK)             // 12

__global__ __launch_bounds__(512) void fused_pp(
    const float* __restrict__ x, const float* __restrict__ W,
    const float* __restrict__ b, const float* __restrict__ en,
    unsigned short* __restrict__ qb, unsigned short* __restrict__ eb)
{
    __shared__ float ws[D_E * (PBK + 1)];
    __shared__ float xs[PTM][PBK];
    __shared__ float red[PTM][4];
    __shared__ float qiv[PTM];

    const int t   = threadIdx.x;
    const int bid = blockIdx.x;

    if (bid >= PROJ_BLOCKS) {
        const int lane = t & 63;
        const int gw   = (bid - PROJ_BLOCKS) * 8 + (t >> 6);
        #pragma unroll 2
        for (int i = 0; i < 8; ++i) {
            const int row = gw * 8 + i;
            if (row >= E_TOT) break;
            const float4 v = *reinterpret_cast<const float4*>(
                en + (size_t)row * D_E + lane * 4);
            float s = v.x*v.x + v.y*v.y + v.z*v.z + v.w*v.w;
            #pragma unroll
            for (int off = 1; off < 64; off <<= 1) s += __shfl_xor(s, off, 64);
            const float sc = 1.0f / fmaxf(sqrtf(s), 1e-8f);
            union { unsigned short u[4]; uint2 d; } o;
            o.u[0] = bf16bits(v.x * sc); o.u[1] = bf16bits(v.y * sc);
            o.u[2] = bf16bits(v.z * sc); o.u[3] = bf16bits(v.w * sc);
            *reinterpret_cast<uint2*>(eb + (size_t)row * D_E + lane * 4) = o.d;
        }
        return;
    }

    const int m0   = bid * PTM;
    const int e    = t & 255;
    const int half = t >> 8;
    const int c4   = t & 15;
    const int rr   = t >> 4;

    float4 wreg[8];
    float  xreg = 0.f;
    float  acc[4] = {0.f, 0.f, 0.f, 0.f};

    #pragma unroll
    for (int i = 0; i < 8; ++i)
        wreg[i] = *reinterpret_cast<const float4*>(
            &W[(size_t)(i * 32 + rr) * D_IN + c4 * 4]);
    xreg = x[(size_t)(m0 + (t >> 6)) * D_IN + (t & 63)];

    for (int rd = 0; rd < PROUNDS; ++rd) {
        #pragma unroll
        for (int i = 0; i < 8; ++i) {
            float* dst = &ws[(i * 32 + rr) * (PBK + 1) + c4 * 4];
            dst[0] = wreg[i].x; dst[1] = wreg[i].y;
            dst[2] = wreg[i].z; dst[3] = wreg[i].w;
        }
        xs[t >> 6][t & 63] = xreg;
        __syncthreads();
        if (rd + 1 < PROUNDS) {
            const int k0 = (rd + 1) * PBK;
            #pragma unroll
            for (int i = 0; i < 8; ++i)
                wreg[i] = *reinterpret_cast<const float4*>(
                    &W[(size_t)(i * 32 + rr) * D_IN + k0 + c4 * 4]);
            xreg = x[(size_t)(m0 + (t >> 6)) * D_IN + k0 + (t & 63)];
        }
        #pragma unroll
        for (int k = 0; k < PBK; ++k) {
            const float wv = ws[e * (PBK + 1) + k];
            #pragma unroll
            for (int j = 0; j < 4; ++j)
                acc[j] = fmaf(xs[half * 4 + j][k], wv, acc[j]);
        }
        __syncthreads();
    }

    const float bias = b[e];
    const int wv4 = (t >> 6) & 3;
    const int lane = t & 63;
    float q[4];
    #pragma unroll
    for (int j = 0; j < 4; ++j) {
        q[j] = tanhf(acc[j] + bias);
        float s = q[j] * q[j];
        #pragma unroll
        for (int off = 1; off < 64; off <<= 1) s += __shfl_xor(s, off, 64);
        if (lane == 0) red[half * 4 + j][wv4] = s;
    }
    __syncthreads();
    if (t < PTM) {
        const float s = red[t][0] + red[t][1] + red[t][2] + red[t][3];
        qiv[t] = 1.0f / fmaxf(sqrtf(s), 1e-8f);
    }
    __syncthreads();
    #pragma unroll
    for (int j = 0; j < 4; ++j)
        qb[(size_t)(m0 + half * 4 + j) * D_E + e] =
            bf16bits(q[j] * qiv[half * 4 + j]);
}

// ---------------------------------------------------------------------------
// Kernel 2 (v15): MLP-maximizing structure.
//   Block = 256 thr (4 waves), tile 32m x 64n; wave = 32m x 16n (acc 8 VGPR).
//   qs 16 KB staged once -> q panel 64 VGPR from LDS (remat-proof; shared by
//   all 4 waves).  Entity K split into 64-wide pieces (8 KB), 3 rotating
//   buffers staged 2 ahead.  LDS = 40 KB -> 4 blocks/CU x 4 waves =
//   16 waves/CU = 4/SIMD, four independent barrier domains per CU.
//   Exact vmcnt ladder (2-op stages, 2-op stores): g<4 -> 2; steady
//   g%4<2 -> 4 else 2; final piece -> 0.  Stores fire-and-forget per tile.
//   Grid 1008 = 63 ngrps x 16 m-blocks, XCD-chunked.
// ---------------------------------------------------------------------------
#define TPB 25                          // n-tiles (64 cols) per block
#define NP (TPB * 4)                    // 100 k-pieces
#define NGRPS 63                        // 63*25*64 = 100800 >= 100000
#define SIM_GRID (NGRPS * 16)           // 1008

__device__ __forceinline__ void stage_piece64(
    const unsigned short* __restrict__ eb, int nt0, int kk,
    unsigned short* dst, int t)
{
    #pragma unroll
    for (int i = 0; i < 2; ++i) {
        const int c  = i * 256 + t;       // 16B-chunk index (0..511)
        const int n  = c >> 3;            // 0..63 entity row
        const int c8 = c & 7;             // chunk within 128B row-piece
        int rg = nt0 + n;
        if (rg >= E_TOT) rg = E_TOT - 1;  // clamp: uniform 2 ops always
        gload_lds16(eb + (size_t)rg * D_E + kk * 64 + ((c8 ^ (n & 7)) << 3),
                    (void*)&dst[(size_t)c << 3]);
    }
}

__global__ __launch_bounds__(256, 4) void sim_kernel(
    const unsigned short* __restrict__ eb, const unsigned short* __restrict__ qb,
    float* __restrict__ out)
{
    __shared__ unsigned short qs[32 * D_E];       // 16 KB
    __shared__ unsigned short es[3][64 * 64];     // 3 x 8 KB   (total 40 KB)

    const int t    = threadIdx.x;
    const int lane = t & 63;
    const int w    = t >> 6;        // 0..3: n sub-panel (16 each)
    const int l15  = lane & 15;
    const int lk   = lane >> 4;     // 0..3

    // XCD-chunked bijective swizzle (1008 = 8*126): 16 consecutive vbids =
    // the 16 m-blocks of one ngrp -> same XCD -> eb slice L2-shared.
    const int vbid = (blockIdx.x & 7) * (SIM_GRID / 8) + (blockIdx.x >> 3);
    const int mg    = vbid & 15;
    const int ngrp  = vbid >> 4;          // 0..62
    const int m0    = mg * 32;
    const int nbase = ngrp * (TPB * 64);  // ngrp * 1600

    // ---- prologue: stage qs (4 ops/thr) then pieces 0,1 (2+2 ops) ----
    #pragma unroll
    for (int i = 0; i < 4; ++i) {
        const int c   = i * 256 + t;      // 0..1023
        const int row = c >> 5;           // 0..31
        const int c16 = c & 31;
        gload_lds16(qb + (size_t)(m0 + row) * D_E + ((c16 ^ (row & 7)) << 3),
                    (void*)&qs[(size_t)c << 3]);
    }
    stage_piece64(eb, nbase, 0, &es[0][0], t);
    stage_piece64(eb, nbase, 1, &es[1][0], t);

    // qs retired (pieces 0,1 in flight) -> q panel into registers (ds_read
    // source: remat-impossible). Shared m-range across all 4 waves.
    asm volatile("s_waitcnt vmcnt(4)" ::: "memory");
    __builtin_amdgcn_sched_barrier(0);
    __builtin_amdgcn_s_barrier();
    __builtin_amdgcn_sched_barrier(0);

    const char* qsb = reinterpret_cast<const char*>(qs);
    bf16x8 qf[2][8];
    #pragma unroll
    for (int mf = 0; mf < 2; ++mf) {
        const int rq = mf * 16 + l15;
        #pragma unroll
        for (int ks = 0; ks < 8; ++ks) {
            const int cb = (ks * 64 + lk * 16) ^ ((rq & 7) << 4);
            qf[mf][ks] = *reinterpret_cast<const bf16x8*>(qsb + rq * 512 + cb);
        }
    }

    f32x4 acc[2];

    #pragma unroll 4
    for (int g = 0; g < NP; ++g) {
        // exact counted ladder: retire stage(g); stores never forced except
        // at the very last piece.
        if (g == NP - 1)      asm volatile("s_waitcnt vmcnt(0)" ::: "memory");
        else if (g < 4)       asm volatile("s_waitcnt vmcnt(2)" ::: "memory");
        else if ((g & 3) < 2) asm volatile("s_waitcnt vmcnt(4)" ::: "memory");
        else                  asm volatile("s_waitcnt vmcnt(2)" ::: "memory");
        __builtin_amdgcn_sched_barrier(0);
        __builtin_amdgcn_s_barrier();
        __builtin_amdgcn_sched_barrier(0);

        // stage piece g+2 into the rotating buffer (safe: reads use g%3)
        if (g + 2 < NP)
            stage_piece64(eb, nbase + ((g + 2) >> 2) * 64, (g + 2) & 3,
                          &es[(g + 2) % 3][0], t);

        if ((g & 3) == 0) {
            acc[0] = (f32x4){0.f, 0.f, 0.f, 0.f};
            acc[1] = (f32x4){0.f, 0.f, 0.f, 0.f};
        }

        const char* esb = reinterpret_cast<const char*>(&es[g % 3][0]);

        __builtin_amdgcn_s_setprio(1);
        #pragma unroll
        for (int s = 0; s < 2; ++s) {
            const int row = w * 16 + l15;
            const int cb  = (s * 64 + lk * 16) ^ ((row & 7) << 4);
            const bf16x8 ef =
                *reinterpret_cast<const bf16x8*>(esb + row * 128 + cb);
            const int ksg = (g & 3) * 2 + s;
            acc[0] = __builtin_amdgcn_mfma_f32_16x16x32_bf16(
                ef, qf[0][ksg], acc[0], 0, 0, 0);
            acc[1] = __builtin_amdgcn_mfma_f32_16x16x32_bf16(
                ef, qf[1][ksg], acc[1], 0, 0, 0);
        }
        __builtin_amdgcn_s_setprio(0);

        // tile end: fire-and-forget stores (>=2 g-steps to drain)
        if ((g & 3) == 3) {
            const int n = nbase + (g >> 2) * 64 + w * 16 + lk * 4;
            if (n < E_TOT) {   // E%4==0 -> whole f32x4 valid
                #pragma unroll
                for (int mf = 0; mf < 2; ++mf) {
                    const int m = m0 + mf * 16 + l15;
                    *reinterpret_cast<f32x4*>(&out[(size_t)m * E_TOT + n]) =
                        acc[mf];
                }
            }
        }
    }
}

// ---------------------------------------------------------------------------
extern "C" void kernel_launch(void* const* d_in, const int* in_sizes, int n_in,
                              void* d_out, int out_size, void* d_ws, size_t ws_size,
                              hipStream_t stream) {
    const float* x  = (const float*)d_in[0];   // [4,128,768]
    const float* W  = (const float*)d_in[1];   // [256,768]
    const float* b  = (const float*)d_in[2];   // [256]
    const float* en = (const float*)d_in[3];   // [100000,256]
    float* out = (float*)d_out;                // [512,100000]

    unsigned short* qb = (unsigned short*)d_ws;                 // 256 KB
    unsigned short* eb = (unsigned short*)((char*)d_ws + (size_t)M_TOT * D_E * 2);

    fused_pp<<<PP_GRID, 512, 0, stream>>>(x, W, b, en, qb, eb); // 1627 blocks
    sim_kernel<<<SIM_GRID, 256, 0, stream>>>(eb, qb, out);      // 1008 blocks
}

// Round 16
// 150.564 us; speedup vs baseline: 1.6867x; 1.0008x over previous
//
#include <hip/hip_runtime.h>
#include <hip/hip_bf16.h>

#define D_IN  768
#define D_E   256
#define M_TOT 512      // B*S
#define E_TOT 100000

typedef __attribute__((ext_vector_type(4))) float f32x4;
typedef __attribute__((ext_vector_type(8))) short bf16x8;

__device__ __forceinline__ unsigned short bf16bits(float f) {
    union { __hip_bfloat16 h; unsigned short u; } c;
    c.h = __float2bfloat16(f);
    return c.u;
}

__device__ __forceinline__ void gload_lds16(const void* g, void* l) {
    __builtin_amdgcn_global_load_lds(
        (const __attribute__((address_space(1))) void*)g,
        (__attribute__((address_space(3))) void*)l, 16, 0, 0);
}

// ---------------------------------------------------------------------------
// Fused prep+proj (unchanged — at BW floor):
//   blocks [0,64):    proj  qb[m][e] = bf16(tanh(x@W^T+b)/||row||)
//   blocks [64,1627): prep  eb[n][k] = bf16(en[n][k]/||en[n]||)
// ---------------------------------------------------------------------------
#define PROJ_BLOCKS 64
#define PREP_BLOCKS 1563
#define PP_GRID (PROJ_BLOCKS + PREP_BLOCKS)
#define PTM 8
#define PBK 64
#define PROUNDS (D_IN / PBK)             // 12

__global__ __launch_bounds__(512) void fused_pp(
    const float* __restrict__ x, const float* __restrict__ W,
    const float* __restrict__ b, const float* __restrict__ en,
    unsigned short* __restrict__ qb, unsigned short* __restrict__ eb)
{
    __shared__ float ws[D_E * (PBK + 1)];
    __shared__ float xs[PTM][PBK];
    __shared__ float red[PTM][4];
    __shared__ float qiv[PTM];

    const int t   = threadIdx.x;
    const int bid = blockIdx.x;

    if (bid >= PROJ_BLOCKS) {
        const int lane = t & 63;
        const int gw   = (bid - PROJ_BLOCKS) * 8 + (t >> 6);
        #pragma unroll 2
        for (int i = 0; i < 8; ++i) {
            const int row = gw * 8 + i;
            if (row >= E_TOT) break;
            const float4 v = *reinterpret_cast<const float4*>(
                en + (size_t)row * D_E + lane * 4);
            float s = v.x*v.x + v.y*v.y + v.z*v.z + v.w*v.w;
            #pragma unroll
            for (int off = 1; off < 64; off <<= 1) s += __shfl_xor(s, off, 64);
            const float sc = 1.0f / fmaxf(sqrtf(s), 1e-8f);
            union { unsigned short u[4]; uint2 d; } o;
            o.u[0] = bf16bits(v.x * sc); o.u[1] = bf16bits(v.y * sc);
            o.u[2] = bf16bits(v.z * sc); o.u[3] = bf16bits(v.w * sc);
            *reinterpret_cast<uint2*>(eb + (size_t)row * D_E + lane * 4) = o.d;
        }
        return;
    }

    const int m0   = bid * PTM;
    const int e    = t & 255;
    const int half = t >> 8;
    const int c4   = t & 15;
    const int rr   = t >> 4;

    float4 wreg[8];
    float  xreg = 0.f;
    float  acc[4] = {0.f, 0.f, 0.f, 0.f};

    #pragma unroll
    for (int i = 0; i < 8; ++i)
        wreg[i] = *reinterpret_cast<const float4*>(
            &W[(size_t)(i * 32 + rr) * D_IN + c4 * 4]);
    xreg = x[(size_t)(m0 + (t >> 6)) * D_IN + (t & 63)];

    for (int rd = 0; rd < PROUNDS; ++rd) {
        #pragma unroll
        for (int i = 0; i < 8; ++i) {
            float* dst = &ws[(i * 32 + rr) * (PBK + 1) + c4 * 4];
            dst[0] = wreg[i].x; dst[1] = wreg[i].y;
            dst[2] = wreg[i].z; dst[3] = wreg[i].w;
        }
        xs[t >> 6][t & 63] = xreg;
        __syncthreads();
        if (rd + 1 < PROUNDS) {
            const int k0 = (rd + 1) * PBK;
            #pragma unroll
            for (int i = 0; i < 8; ++i)
                wreg[i] = *reinterpret_cast<const float4*>(
                    &W[(size_t)(i * 32 + rr) * D_IN + k0 + c4 * 4]);
            xreg = x[(size_t)(m0 + (t >> 6)) * D_IN + k0 + (t & 63)];
        }
        #pragma unroll
        for (int k = 0; k < PBK; ++k) {
            const float wv = ws[e * (PBK + 1) + k];
            #pragma unroll
            for (int j = 0; j < 4; ++j)
                acc[j] = fmaf(xs[half * 4 + j][k], wv, acc[j]);
        }
        __syncthreads();
    }

    const float bias = b[e];
    const int wv4 = (t >> 6) & 3;
    const int lane = t & 63;
    float q[4];
    #pragma unroll
    for (int j = 0; j < 4; ++j) {
        q[j] = tanhf(acc[j] + bias);
        float s = q[j] * q[j];
        #pragma unroll
        for (int off = 1; off < 64; off <<= 1) s += __shfl_xor(s, off, 64);
        if (lane == 0) red[half * 4 + j][wv4] = s;
    }
    __syncthreads();
    if (t < PTM) {
        const float s = red[t][0] + red[t][1] + red[t][2] + red[t][3];
        qiv[t] = 1.0f / fmaxf(sqrtf(s), 1e-8f);
    }
    __syncthreads();
    #pragma unroll
    for (int j = 0; j < 4; ++j)
        qb[(size_t)(m0 + half * 4 + j) * D_E + e] =
            bf16bits(q[j] * qiv[half * 4 + j]);
}

// ---------------------------------------------------------------------------
// Kernel 2 (v16): r10 VERBATIM except store handling — paired-tile store
// bursts for 2x DRAM row density, with an EXACT vmcnt ladder.
//   accA (even tiles) + accB (odd tiles) held in regs; at the top of even
//   tile tt>=2 (right after issuing stage(tt+1)) the pair (tt-2,tt-1) is
//   stored as one 8-instr burst: each output row receives 512B CONTIGUOUS.
//   Ladder (exact, in-order): tt<2 -> vmcnt(0); odd tt -> vmcnt(8) [the 8
//   burst stores are the only ops newer than stage(tt)]; even tt -> vmcnt(0)
//   [stage(tt) is newest; stores are 2 tiles old, already drained].
// ---------------------------------------------------------------------------
#define BM 128
#define BN 64
#define TPB 25
#define NGRPN 63                        // 63*25*64 = 100800 >= 100000
#define SIM_GRID (NGRPN * (M_TOT / BM))   // 252

__global__ __launch_bounds__(512, 2) void sim_kernel(
    const unsigned short* __restrict__ eb, const unsigned short* __restrict__ qb,
    float* __restrict__ out)
{
    __shared__ unsigned short qs[BM * D_E];       // 64 KB
    __shared__ unsigned short es[2][BN * D_E];    // 2 x 32 KB

    const int t    = threadIdx.x;
    const int lane = t & 63;
    const int wid  = t >> 6;        // 0..7
    const int l15  = lane & 15;
    const int lk   = lane >> 4;     // 0..3
    const int wm   = (wid >> 1) * 32;   // 0,32,64,96
    const int wn   = (wid & 1) * 32;    // 0,32

    int vbid;
    {
        const int q = SIM_GRID >> 3, r = SIM_GRID & 7;   // 31, 4
        const int xcd = blockIdx.x & 7, rk = blockIdx.x >> 3;
        vbid = (xcd < r ? xcd * (q + 1) : r * (q + 1) + (xcd - r) * q) + rk;
    }
    const int mg    = vbid & 3;
    const int ngrp  = vbid >> 2;            // 0..62
    const int m0    = mg * BM;
    const int nbase = ngrp * (TPB * BN);    // ngrp * 1600

    // ---- prologue: stage q tile (8 chunks/thr) + entity tile 0 (4) ----
    #pragma unroll
    for (int i = 0; i < 8; ++i) {
        const int c   = i * 512 + t;
        const int row = c >> 5;             // 0..127
        const int c16 = c & 31;
        const unsigned short* src =
            qb + (size_t)(m0 + row) * D_E + ((c16 ^ (row & 7)) << 3);
        gload_lds16(src, (void*)&qs[(size_t)c << 3]);
    }
    #pragma unroll
    for (int i = 0; i < 4; ++i) {
        const int c   = i * 512 + t;
        const int row = c >> 5;             // 0..63
        const int c16 = c & 31;
        int rg = nbase + row; if (rg >= E_TOT) rg = E_TOT - 1;
        const unsigned short* src =
            eb + (size_t)rg * D_E + ((c16 ^ (row & 7)) << 3);
        gload_lds16(src, (void*)&es[0][(size_t)c << 3]);
    }

    const char* qsb = reinterpret_cast<const char*>(qs);

    f32x4 accA[2][2], accB[2][2];

    // store one tile's 2x2 acc fragments (4 f32x4 stores)
    #define STORE_TILE(ACC, N0T)                                              \
        do {                                                                  \
            _Pragma("unroll")                                                 \
            for (int mf_ = 0; mf_ < 2; ++mf_) {                               \
                const int m_ = m0 + wm + mf_ * 16 + l15;                      \
                _Pragma("unroll")                                             \
                for (int nf_ = 0; nf_ < 2; ++nf_) {                           \
                    const int n_ = (N0T) + wn + nf_ * 16 + lk * 4;            \
                    if (n_ < E_TOT)                                           \
                        *reinterpret_cast<f32x4*>(                            \
                            &out[(size_t)m_ * E_TOT + n_]) = ACC[mf_][nf_];   \
                }                                                             \
            }                                                                 \
        } while (0)

    int tt;
    for (tt = 0; tt < TPB; ++tt) {
        const int n0 = nbase + tt * BN;
        if (n0 >= E_TOT) break;             // block-uniform

        // ---- exact counted ladder ----
        if (tt < 2 || (tt & 1) == 0)
            asm volatile("s_waitcnt vmcnt(0)" ::: "memory");
        else
            asm volatile("s_waitcnt vmcnt(8)" ::: "memory");
        __builtin_amdgcn_sched_barrier(0);
        __builtin_amdgcn_s_barrier();
        __builtin_amdgcn_sched_barrier(0);

        const int cur = tt & 1;

        // stage next tile FIRST (so the pair burst below is newer than it;
        // odd tiles then keep the burst in flight with vmcnt(8))
        const int nn0 = n0 + BN;
        if (tt + 1 < TPB && nn0 < E_TOT) {
            #pragma unroll
            for (int i = 0; i < 4; ++i) {
                const int c   = i * 512 + t;
                const int row = c >> 5;
                const int c16 = c & 31;
                int rg = nn0 + row; if (rg >= E_TOT) rg = E_TOT - 1;
                const unsigned short* src =
                    eb + (size_t)rg * D_E + ((c16 ^ (row & 7)) << 3);
                gload_lds16(src, (void*)&es[cur ^ 1][(size_t)c << 3]);
            }
        }

        // pair store burst: tiles (tt-2, tt-1) -> each row gets 512B contig
        if (tt >= 2 && (tt & 1) == 0) {
            STORE_TILE(accA, nbase + (tt - 2) * BN);
            STORE_TILE(accB, nbase + (tt - 1) * BN);
        }

        const char* esb = reinterpret_cast<const char*>(&es[cur][0]);

        if (cur == 0) {
            #pragma unroll
            for (int mf = 0; mf < 2; ++mf)
                #pragma unroll
                for (int nf = 0; nf < 2; ++nf)
                    accA[mf][nf] = (f32x4){0.f, 0.f, 0.f, 0.f};
        } else {
            #pragma unroll
            for (int mf = 0; mf < 2; ++mf)
                #pragma unroll
                for (int nf = 0; nf < 2; ++nf)
                    accB[mf][nf] = (f32x4){0.f, 0.f, 0.f, 0.f};
        }

        __builtin_amdgcn_s_setprio(1);
        #pragma unroll
        for (int ks = 0; ks < 8; ++ks) {
            const int kb = ks * 64 + lk * 16;
            bf16x8 ef[2];
            #pragma unroll
            for (int nf = 0; nf < 2; ++nf) {
                const int row = wn + nf * 16 + l15;
                const int cb  = kb ^ ((row & 7) << 4);
                ef[nf] = *reinterpret_cast<const bf16x8*>(esb + row * 512 + cb);
            }
            #pragma unroll
            for (int mf = 0; mf < 2; ++mf) {
                const int rq  = wm + mf * 16 + l15;
                const int cbq = kb ^ ((rq & 7) << 4);
                const bf16x8 qf =
                    *reinterpret_cast<const bf16x8*>(qsb + rq * 512 + cbq);
                if (cur == 0) {
                    accA[mf][0] = __builtin_amdgcn_mfma_f32_16x16x32_bf16(
                        ef[0], qf, accA[mf][0], 0, 0, 0);
                    accA[mf][1] = __builtin_amdgcn_mfma_f32_16x16x32_bf16(
                        ef[1], qf, accA[mf][1], 0, 0, 0);
                } else {
                    accB[mf][0] = __builtin_amdgcn_mfma_f32_16x16x32_bf16(
                        ef[0], qf, accB[mf][0], 0, 0, 0);
                    accB[mf][1] = __builtin_amdgcn_mfma_f32_16x16x32_bf16(
                        ef[1], qf, accB[mf][1], 0, 0, 0);
                }
            }
        }
        __builtin_amdgcn_s_setprio(0);
    }

    // ---- flush unstored tiles ----
    const int lc = tt - 1;                  // last computed tile
    if (lc >= 0) {
        if (lc & 1) {                       // accA(lc-1) and accB(lc) pending
            STORE_TILE(accA, nbase + (lc - 1) * BN);
            STORE_TILE(accB, nbase + lc * BN);
        } else {                            // only accA(lc) pending
            STORE_TILE(accA, nbase + lc * BN);
        }
    }
    #undef STORE_TILE
}

// ---------------------------------------------------------------------------
extern "C" void kernel_launch(void* const* d_in, const int* in_sizes, int n_in,
                              void* d_out, int out_size, void* d_ws, size_t ws_size,
                              hipStream_t stream) {
    const float* x  = (const float*)d_in[0];   // [4,128,768]
    const float* W  = (const float*)d_in[1];   // [256,768]
    const float* b  = (const float*)d_in[2];   // [256]
    const float* en = (const float*)d_in[3];   // [100000,256]
    float* out = (float*)d_out;                // [512,100000]

    unsigned short* qb = (unsigned short*)d_ws;                 // 256 KB
    unsigned short* eb = (unsigned short*)((char*)d_ws + (size_t)M_TOT * D_E * 2);

    fused_pp<<<PP_GRID, 512, 0, stream>>>(x, W, b, en, qb, eb); // 1627 blocks
    sim_kernel<<<SIM_GRID, 512, 0, stream>>>(eb, qb, out);      // 252 blocks
}

// Round 17
// 141.528 us; speedup vs baseline: 1.7944x; 1.0638x over previous
//
#include <hip/hip_runtime.h>
#include <hip/hip_bf16.h>

#define D_IN  768
#define D_E   256
#define M_TOT 512      // B*S
#define E_TOT 100000

typedef __attribute__((ext_vector_type(4))) float f32x4;
typedef __attribute__((ext_vector_type(8))) short bf16x8;

__device__ __forceinline__ unsigned short bf16bits(float f) {
    union { __hip_bfloat16 h; unsigned short u; } c;
    c.h = __float2bfloat16(f);
    return c.u;
}

__device__ __forceinline__ void gload_lds16(const void* g, void* l) {
    __builtin_amdgcn_global_load_lds(
        (const __attribute__((address_space(1))) void*)g,
        (__attribute__((address_space(3))) void*)l, 16, 0, 0);
}

// ---------------------------------------------------------------------------
// Fused prep+proj (unchanged — at BW floor):
//   blocks [0,64):    proj  qb[m][e] = bf16(tanh(x@W^T+b)/||row||)
//   blocks [64,1627): prep  eb[n][k] = bf16(en[n][k]/||en[n]||)
// ---------------------------------------------------------------------------
#define PROJ_BLOCKS 64
#define PREP_BLOCKS 1563
#define PP_GRID (PROJ_BLOCKS + PREP_BLOCKS)
#define PTM 8
#define PBK 64
#define PROUNDS (D_IN / PBK)             // 12

__global__ __launch_bounds__(512) void fused_pp(
    const float* __restrict__ x, const float* __restrict__ W,
    const float* __restrict__ b, const float* __restrict__ en,
    unsigned short* __restrict__ qb, unsigned short* __restrict__ eb)
{
    __shared__ float ws[D_E * (PBK + 1)];
    __shared__ float xs[PTM][PBK];
    __shared__ float red[PTM][4];
    __shared__ float qiv[PTM];

    const int t   = threadIdx.x;
    const int bid = blockIdx.x;

    if (bid >= PROJ_BLOCKS) {
        const int lane = t & 63;
        const int gw   = (bid - PROJ_BLOCKS) * 8 + (t >> 6);
        #pragma unroll 2
        for (int i = 0; i < 8; ++i) {
            const int row = gw * 8 + i;
            if (row >= E_TOT) break;
            const float4 v = *reinterpret_cast<const float4*>(
                en + (size_t)row * D_E + lane * 4);
            float s = v.x*v.x + v.y*v.y + v.z*v.z + v.w*v.w;
            #pragma unroll
            for (int off = 1; off < 64; off <<= 1) s += __shfl_xor(s, off, 64);
            const float sc = 1.0f / fmaxf(sqrtf(s), 1e-8f);
            union { unsigned short u[4]; uint2 d; } o;
            o.u[0] = bf16bits(v.x * sc); o.u[1] = bf16bits(v.y * sc);
            o.u[2] = bf16bits(v.z * sc); o.u[3] = bf16bits(v.w * sc);
            *reinterpret_cast<uint2*>(eb + (size_t)row * D_E + lane * 4) = o.d;
        }
        return;
    }

    const int m0   = bid * PTM;
    const int e    = t & 255;
    const int half = t >> 8;
    const int c4   = t & 15;
    const int rr   = t >> 4;

    float4 wreg[8];
    float  xreg = 0.f;
    float  acc[4] = {0.f, 0.f, 0.f, 0.f};

    #pragma unroll
    for (int i = 0; i < 8; ++i)
        wreg[i] = *reinterpret_cast<const float4*>(
            &W[(size_t)(i * 32 + rr) * D_IN + c4 * 4]);
    xreg = x[(size_t)(m0 + (t >> 6)) * D_IN + (t & 63)];

    for (int rd = 0; rd < PROUNDS; ++rd) {
        #pragma unroll
        for (int i = 0; i < 8; ++i) {
            float* dst = &ws[(i * 32 + rr) * (PBK + 1) + c4 * 4];
            dst[0] = wreg[i].x; dst[1] = wreg[i].y;
            dst[2] = wreg[i].z; dst[3] = wreg[i].w;
        }
        xs[t >> 6][t & 63] = xreg;
        __syncthreads();
        if (rd + 1 < PROUNDS) {
            const int k0 = (rd + 1) * PBK;
            #pragma unroll
            for (int i = 0; i < 8; ++i)
                wreg[i] = *reinterpret_cast<const float4*>(
                    &W[(size_t)(i * 32 + rr) * D_IN + k0 + c4 * 4]);
            xreg = x[(size_t)(m0 + (t >> 6)) * D_IN + k0 + (t & 63)];
        }
        #pragma unroll
        for (int k = 0; k < PBK; ++k) {
            const float wv = ws[e * (PBK + 1) + k];
            #pragma unroll
            for (int j = 0; j < 4; ++j)
                acc[j] = fmaf(xs[half * 4 + j][k], wv, acc[j]);
        }
        __syncthreads();
    }

    const float bias = b[e];
    const int wv4 = (t >> 6) & 3;
    const int lane = t & 63;
    float q[4];
    #pragma unroll
    for (int j = 0; j < 4; ++j) {
        q[j] = tanhf(acc[j] + bias);
        float s = q[j] * q[j];
        #pragma unroll
        for (int off = 1; off < 64; off <<= 1) s += __shfl_xor(s, off, 64);
        if (lane == 0) red[half * 4 + j][wv4] = s;
    }
    __syncthreads();
    if (t < PTM) {
        const float s = red[t][0] + red[t][1] + red[t][2] + red[t][3];
        qiv[t] = 1.0f / fmaxf(sqrtf(s), 1e-8f);
    }
    __syncthreads();
    #pragma unroll
    for (int j = 0; j < 4; ++j)
        qb[(size_t)(m0 + half * 4 + j) * D_E + e] =
            bf16bits(q[j] * qiv[half * 4 + j]);
}

// ---------------------------------------------------------------------------
// Kernel 2 (v17): r10 compute/staging + TRANSACTION-DENSE epilogue.
//   Theory: HBM is txn-limited (~30 G/s). r10's MFMA-layout stores are 16 x
//   64B segments/instr -> 3.2M txns -> 107 us floor. Fix: acc -> swizzled
//   LDS transpose buffer (dbuf in the 64 KB freed by moving q to regs),
//   read back row-linear next tile -> each wave-store = 256B contiguous of
//   ONE row -> ~1M txns.
//   Layout: poolA 64 KB = qs (prologue) then tbuf[2][32 KB]; es[2][32 KB].
//   Per tile: [vmcnt(16); lgkmcnt(0); barrier] -> stage(tt+1) -> readback+
//   store(tt-1) from tbuf[cur^1] -> compute(tt) from es[cur] -> twrite(tt)
//   -> tbuf[cur]. Stores never forced (vmcnt(16) = stage 4 + stores 16 in
//   flight); epilogue flushes the last tile.
// ---------------------------------------------------------------------------
#define BM 128
#define BN 64
#define TPB 25
#define NGRPN 63                        // 63*25*64 = 100800 >= 100000
#define SIM_GRID (NGRPN * (M_TOT / BM))   // 252

__global__ __launch_bounds__(512, 2) void sim_kernel(
    const unsigned short* __restrict__ eb, const unsigned short* __restrict__ qb,
    float* __restrict__ out)
{
    __shared__ unsigned short poolA[32768];       // 64 KB: qs -> tbuf[2]
    __shared__ unsigned short es[2][BN * D_E];    // 2 x 32 KB

    const int t    = threadIdx.x;
    const int lane = t & 63;
    const int wid  = t >> 6;        // 0..7
    const int l15  = lane & 15;
    const int lk   = lane >> 4;     // 0..3
    const int wm   = (wid >> 1) * 32;   // 0,32,64,96
    const int wn   = (wid & 1) * 32;    // 0,32

    int vbid;
    {
        const int q = SIM_GRID >> 3, r = SIM_GRID & 7;   // 31, 4
        const int xcd = blockIdx.x & 7, rk = blockIdx.x >> 3;
        vbid = (xcd < r ? xcd * (q + 1) : r * (q + 1) + (xcd - r) * q) + rk;
    }
    const int mg    = vbid & 3;
    const int ngrp  = vbid >> 2;            // 0..62
    const int m0    = mg * BM;
    const int nbase = ngrp * (TPB * BN);    // ngrp * 1600

    int nt = (E_TOT - nbase + BN - 1) / BN;
    if (nt > TPB) nt = TPB;                 // >= 13 always

    // ---- prologue: stage qs (8 ops/thr) then entity tile 0 (4 ops) ----
    #pragma unroll
    for (int i = 0; i < 8; ++i) {
        const int c   = i * 512 + t;
        const int row = c >> 5;             // 0..127
        const int c16 = c & 31;
        gload_lds16(qb + (size_t)(m0 + row) * D_E + ((c16 ^ (row & 7)) << 3),
                    (void*)&poolA[(size_t)c << 3]);
    }
    #pragma unroll
    for (int i = 0; i < 4; ++i) {
        const int c   = i * 512 + t;
        const int row = c >> 5;             // 0..63
        const int c16 = c & 31;
        int rg = nbase + row; if (rg >= E_TOT) rg = E_TOT - 1;
        gload_lds16(eb + (size_t)rg * D_E + ((c16 ^ (row & 7)) << 3),
                    (void*)&es[0][(size_t)c << 3]);
    }

    // qs retired (es0 in flight) -> barrier -> q panel into registers
    asm volatile("s_waitcnt vmcnt(4)" ::: "memory");
    __builtin_amdgcn_sched_barrier(0);
    __builtin_amdgcn_s_barrier();
    __builtin_amdgcn_sched_barrier(0);

    const char* qsb = reinterpret_cast<const char*>(poolA);
    bf16x8 qf[2][8];
    #pragma unroll
    for (int mf = 0; mf < 2; ++mf) {
        const int rq = wm + mf * 16 + l15;
        #pragma unroll
        for (int ks = 0; ks < 8; ++ks) {
            const int cb = (ks * 64 + lk * 16) ^ ((rq & 7) << 4);
            qf[mf][ks] = *reinterpret_cast<const bf16x8*>(qsb + rq * 512 + cb);
        }
    }
    asm volatile("s_waitcnt lgkmcnt(0)" ::: "memory");  // qf loaded before any
    __builtin_amdgcn_sched_barrier(0);                  // wave reuses poolA

    char* tb[2];
    tb[0] = reinterpret_cast<char*>(poolA);             // 32 KB
    tb[1] = reinterpret_cast<char*>(poolA) + 32768;     // 32 KB

    f32x4 acc[2][2];

    for (int tt = 0; tt < nt; ++tt) {
        const int n0  = nbase + tt * BN;
        const int cur = tt & 1;

        // ---- exact ladder: retire stage(tt); keep stores in flight ----
        if (tt < 2) asm volatile("s_waitcnt vmcnt(0) lgkmcnt(0)" ::: "memory");
        else        asm volatile("s_waitcnt vmcnt(16) lgkmcnt(0)" ::: "memory");
        __builtin_amdgcn_sched_barrier(0);
        __builtin_amdgcn_s_barrier();
        __builtin_amdgcn_sched_barrier(0);

        // stage next entity tile
        if (tt + 1 < nt) {
            const int nn0 = n0 + BN;
            #pragma unroll
            for (int i = 0; i < 4; ++i) {
                const int c   = i * 512 + t;
                const int row = c >> 5;
                const int c16 = c & 31;
                int rg = nn0 + row; if (rg >= E_TOT) rg = E_TOT - 1;
                gload_lds16(eb + (size_t)rg * D_E + ((c16 ^ (row & 7)) << 3),
                            (void*)&es[cur ^ 1][(size_t)c << 3]);
            }
        }

        // readback + 256B-contiguous stores of tile tt-1 from tbuf[cur^1]
        if (tt >= 1) {
            const char* tbp = tb[cur ^ 1];
            const int  n0p  = n0 - BN;
            float v[16];
            #pragma unroll
            for (int j = 0; j < 16; ++j) {
                const int row = wid * 16 + j;
                v[j] = *reinterpret_cast<const float*>(
                    tbp + row * 256 + ((lane * 4) ^ ((row & 7) << 4)));
            }
            const int n = n0p + lane;
            if (n < E_TOT) {
                #pragma unroll
                for (int j = 0; j < 16; ++j) {
                    const int row = wid * 16 + j;
                    out[(size_t)(m0 + row) * E_TOT + n] = v[j];
                }
            }
        }

        // compute tile tt
        #pragma unroll
        for (int mf = 0; mf < 2; ++mf)
            #pragma unroll
            for (int nf = 0; nf < 2; ++nf)
                acc[mf][nf] = (f32x4){0.f, 0.f, 0.f, 0.f};

        const char* esb = reinterpret_cast<const char*>(&es[cur][0]);
        __builtin_amdgcn_s_setprio(1);
        #pragma unroll
        for (int ks = 0; ks < 8; ++ks) {
            const int kb = ks * 64 + lk * 16;
            bf16x8 ef[2];
            #pragma unroll
            for (int nf = 0; nf < 2; ++nf) {
                const int row = wn + nf * 16 + l15;
                const int cb  = kb ^ ((row & 7) << 4);
                ef[nf] = *reinterpret_cast<const bf16x8*>(esb + row * 512 + cb);
            }
            #pragma unroll
            for (int mf = 0; mf < 2; ++mf) {
                acc[mf][0] = __builtin_amdgcn_mfma_f32_16x16x32_bf16(
                    ef[0], qf[mf][ks], acc[mf][0], 0, 0, 0);
                acc[mf][1] = __builtin_amdgcn_mfma_f32_16x16x32_bf16(
                    ef[1], qf[mf][ks], acc[mf][1], 0, 0, 0);
            }
        }
        __builtin_amdgcn_s_setprio(0);

        // transpose-write acc -> tbuf[cur] (swizzled; read back next tile)
        {
            char* tbp = tb[cur];
            #pragma unroll
            for (int mf = 0; mf < 2; ++mf) {
                const int mrow = wm + mf * 16 + l15;
                #pragma unroll
                for (int nf = 0; nf < 2; ++nf) {
                    const int colb = (wn + nf * 16 + lk * 4) * 4;
                    *reinterpret_cast<f32x4*>(
                        tbp + mrow * 256 + (colb ^ ((mrow & 7) << 4))) =
                        acc[mf][nf];
                }
            }
        }
    }

    // ---- epilogue: flush last tile ----
    asm volatile("s_waitcnt lgkmcnt(0)" ::: "memory");
    __builtin_amdgcn_sched_barrier(0);
    __builtin_amdgcn_s_barrier();
    __builtin_amdgcn_sched_barrier(0);
    {
        const char* tbp = tb[(nt - 1) & 1];
        const int  n0p  = nbase + (nt - 1) * BN;
        float v[16];
        #pragma unroll
        for (int j = 0; j < 16; ++j) {
            const int row = wid * 16 + j;
            v[j] = *reinterpret_cast<const float*>(
                tbp + row * 256 + ((lane * 4) ^ ((row & 7) << 4)));
        }
        const int n = n0p + lane;
        if (n < E_TOT) {
            #pragma unroll
            for (int j = 0; j < 16; ++j) {
                const int row = wid * 16 + j;
                out[(size_t)(m0 + row) * E_TOT + n] = v[j];
            }
        }
    }
}

// ---------------------------------------------------------------------------
extern "C" void kernel_launch(void* const* d_in, const int* in_sizes, int n_in,
                              void* d_out, int out_size, void* d_ws, size_t ws_size,
                              hipStream_t stream) {
    const float* x  = (const float*)d_in[0];   // [4,128,768]
    const float* W  = (const float*)d_in[1];   // [256,768]
    const float* b  = (const float*)d_in[2];   // [256]
    const float* en = (const float*)d_in[3];   // [100000,256]
    float* out = (float*)d_out;                // [512,100000]

    unsigned short* qb = (unsigned short*)d_ws;                 // 256 KB
    unsigned short* eb = (unsigned short*)((char*)d_ws + (size_t)M_TOT * D_E * 2);

    fused_pp<<<PP_GRID, 512, 0, stream>>>(x, W, b, en, qb, eb); // 1627 blocks
    sim_kernel<<<SIM_GRID, 512, 0, stream>>>(eb, qb, out);      // 252 blocks
}

// Round 18
// 131.329 us; speedup vs baseline: 1.9337x; 1.0777x over previous
//
#include <hip/hip_runtime.h>
#include <hip/hip_bf16.h>

#define D_IN  768
#define D_E   256
#define M_TOT 512      // B*S
#define E_TOT 100000

typedef __attribute__((ext_vector_type(4))) float f32x4;
typedef __attribute__((ext_vector_type(8))) short bf16x8;

__device__ __forceinline__ unsigned short bf16bits(float f) {
    union { __hip_bfloat16 h; unsigned short u; } c;
    c.h = __float2bfloat16(f);
    return c.u;
}

__device__ __forceinline__ void gload_lds16(const void* g, void* l) {
    __builtin_amdgcn_global_load_lds(
        (const __attribute__((address_space(1))) void*)g,
        (__attribute__((address_space(3))) void*)l, 16, 0, 0);
}

// ---------------------------------------------------------------------------
// Fused prep+proj (r9, at BW floor):
//   blocks [0,64):    proj  qb[m][e] = bf16(tanh(x@W^T+b)/||row||)
//   blocks [64,1627): prep  eb[n][k] = bf16(en[n][k]/||en[n]||)
// ---------------------------------------------------------------------------
#define PROJ_BLOCKS 64
#define PREP_BLOCKS 1563                 // 1563*64 = 100032 >= 100000
#define PP_GRID (PROJ_BLOCKS + PREP_BLOCKS)
#define PTM 8
#define PBK 64
#define PROUNDS (D_IN / PBK)             // 12

__global__ __launch_bounds__(512) void fused_pp(
    const float* __restrict__ x, const float* __restrict__ W,
    const float* __restrict__ b, const float* __restrict__ en,
    unsigned short* __restrict__ qb, unsigned short* __restrict__ eb)
{
    __shared__ float ws[D_E * (PBK + 1)];   // 65 KB (proj only)
    __shared__ float xs[PTM][PBK];
    __shared__ float red[PTM][4];
    __shared__ float qiv[PTM];

    const int t   = threadIdx.x;
    const int bid = blockIdx.x;

    if (bid >= PROJ_BLOCKS) {
        const int lane = t & 63;
        const int gw   = (bid - PROJ_BLOCKS) * 8 + (t >> 6);
        #pragma unroll 2
        for (int i = 0; i < 8; ++i) {
            const int row = gw * 8 + i;
            if (row >= E_TOT) break;
            const float4 v = *reinterpret_cast<const float4*>(
                en + (size_t)row * D_E + lane * 4);
            float s = v.x*v.x + v.y*v.y + v.z*v.z + v.w*v.w;
            #pragma unroll
            for (int off = 1; off < 64; off <<= 1) s += __shfl_xor(s, off, 64);
            const float sc = 1.0f / fmaxf(sqrtf(s), 1e-8f);
            union { unsigned short u[4]; uint2 d; } o;
            o.u[0] = bf16bits(v.x * sc); o.u[1] = bf16bits(v.y * sc);
            o.u[2] = bf16bits(v.z * sc); o.u[3] = bf16bits(v.w * sc);
            *reinterpret_cast<uint2*>(eb + (size_t)row * D_E + lane * 4) = o.d;
        }
        return;
    }

    const int m0   = bid * PTM;
    const int e    = t & 255;
    const int half = t >> 8;
    const int c4   = t & 15;
    const int rr   = t >> 4;

    float4 wreg[8];
    float  xreg = 0.f;
    float  acc[4] = {0.f, 0.f, 0.f, 0.f};

    #pragma unroll
    for (int i = 0; i < 8; ++i)
        wreg[i] = *reinterpret_cast<const float4*>(
            &W[(size_t)(i * 32 + rr) * D_IN + c4 * 4]);
    xreg = x[(size_t)(m0 + (t >> 6)) * D_IN + (t & 63)];

    for (int rd = 0; rd < PROUNDS; ++rd) {
        #pragma unroll
        for (int i = 0; i < 8; ++i) {
            float* dst = &ws[(i * 32 + rr) * (PBK + 1) + c4 * 4];
            dst[0] = wreg[i].x; dst[1] = wreg[i].y;
            dst[2] = wreg[i].z; dst[3] = wreg[i].w;
        }
        xs[t >> 6][t & 63] = xreg;
        __syncthreads();
        if (rd + 1 < PROUNDS) {
            const int k0 = (rd + 1) * PBK;
            #pragma unroll
            for (int i = 0; i < 8; ++i)
                wreg[i] = *reinterpret_cast<const float4*>(
                    &W[(size_t)(i * 32 + rr) * D_IN + k0 + c4 * 4]);
            xreg = x[(size_t)(m0 + (t >> 6)) * D_IN + k0 + (t & 63)];
        }
        #pragma unroll
        for (int k = 0; k < PBK; ++k) {
            const float wv = ws[e * (PBK + 1) + k];
            #pragma unroll
            for (int j = 0; j < 4; ++j)
                acc[j] = fmaf(xs[half * 4 + j][k], wv, acc[j]);
        }
        __syncthreads();
    }

    const float bias = b[e];
    const int wv4 = (t >> 6) & 3;
    const int lane = t & 63;
    float q[4];
    #pragma unroll
    for (int j = 0; j < 4; ++j) {
        q[j] = tanhf(acc[j] + bias);
        float s = q[j] * q[j];
        #pragma unroll
        for (int off = 1; off < 64; off <<= 1) s += __shfl_xor(s, off, 64);
        if (lane == 0) red[half * 4 + j][wv4] = s;
    }
    __syncthreads();
    if (t < PTM) {
        const float s = red[t][0] + red[t][1] + red[t][2] + red[t][3];
        qiv[t] = 1.0f / fmaxf(sqrtf(s), 1e-8f);
    }
    __syncthreads();
    #pragma unroll
    for (int j = 0; j < 4; ++j)
        qb[(size_t)(m0 + half * 4 + j) * D_E + e] =
            bf16bits(q[j] * qiv[half * 4 + j]);
}

// ---------------------------------------------------------------------------
// Kernel 2 (v10 — the empirical best, r10 verbatim): pure-LDS compute core,
// counted-vmcnt sync (T4), raw s_barrier, setprio around MFMA:
//   per tile: vmcnt(4) [this tile's stage done; prev stores stay in flight]
//             -> s_barrier -> issue next stage -> ds_read+MFMA (setprio)
//             -> stores (drain during the NEXT tile, never waited on).
// One barrier, one counted waitcnt per tile. 8 waves, 128 KB LDS, grid 252.
// ---------------------------------------------------------------------------
#define BM 128
#define BN 64
#define TPB 25
#define NGRPN 63                        // 63*25*64 = 100800 >= 100000
#define SIM_GRID (NGRPN * (M_TOT / BM))   // 252

__global__ __launch_bounds__(512, 2) void sim_kernel(
    const unsigned short* __restrict__ eb, const unsigned short* __restrict__ qb,
    float* __restrict__ out)
{
    __shared__ unsigned short qs[BM * D_E];       // 64 KB
    __shared__ unsigned short es[2][BN * D_E];    // 2 x 32 KB

    const int t    = threadIdx.x;
    const int lane = t & 63;
    const int wid  = t >> 6;        // 0..7
    const int l15  = lane & 15;
    const int lk   = lane >> 4;     // 0..3
    const int wm   = (wid >> 1) * 32;   // 0,32,64,96
    const int wn   = (wid & 1) * 32;    // 0,32

    int vbid;
    {
        const int q = SIM_GRID >> 3, r = SIM_GRID & 7;   // 31, 4
        const int xcd = blockIdx.x & 7, rk = blockIdx.x >> 3;
        vbid = (xcd < r ? xcd * (q + 1) : r * (q + 1) + (xcd - r) * q) + rk;
    }
    const int mg    = vbid & 3;
    const int ngrp  = vbid >> 2;            // 0..62
    const int m0    = mg * BM;
    const int nbase = ngrp * (TPB * BN);    // ngrp * 1600

    // ---- prologue: stage q tile (8 chunks/thr) + entity tile 0 (4) ----
    #pragma unroll
    for (int i = 0; i < 8; ++i) {
        const int c   = i * 512 + t;
        const int row = c >> 5;             // 0..127
        const int c16 = c & 31;
        const unsigned short* src =
            qb + (size_t)(m0 + row) * D_E + ((c16 ^ (row & 7)) << 3);
        gload_lds16(src, (void*)&qs[(size_t)c << 3]);
    }
    #pragma unroll
    for (int i = 0; i < 4; ++i) {
        const int c   = i * 512 + t;
        const int row = c >> 5;             // 0..63
        const int c16 = c & 31;
        int rg = nbase + row; if (rg >= E_TOT) rg = E_TOT - 1;
        const unsigned short* src =
            eb + (size_t)rg * D_E + ((c16 ^ (row & 7)) << 3);
        gload_lds16(src, (void*)&es[0][(size_t)c << 3]);
    }

    const char* qsb = reinterpret_cast<const char*>(qs);

    for (int tt = 0; tt < TPB; ++tt) {
        const int n0 = nbase + tt * BN;
        if (n0 >= E_TOT) break;             // block-uniform

        // wait: this tile's stage (issued last iter / prologue) retired.
        // vmcnt(4) leaves the previous tile's 4 stores in flight (T4).
        if (tt == 0) {
            asm volatile("s_waitcnt vmcnt(0)" ::: "memory");
        } else {
            asm volatile("s_waitcnt vmcnt(4)" ::: "memory");
        }
        __builtin_amdgcn_s_barrier();       // all waves' stage portions done
        __builtin_amdgcn_sched_barrier(0);  // pin: nothing hoists above

        // issue next tile's stage into the other buffer (after barrier:
        // no wave can still be reading buf^1 — its reads finished before
        // the PREVIOUS barrier).
        const int cur = tt & 1;
        const int nn0 = n0 + BN;
        if (tt + 1 < TPB && nn0 < E_TOT) {
            #pragma unroll
            for (int i = 0; i < 4; ++i) {
                const int c   = i * 512 + t;
                const int row = c >> 5;
                const int c16 = c & 31;
                int rg = nn0 + row; if (rg >= E_TOT) rg = E_TOT - 1;
                const unsigned short* src =
                    eb + (size_t)rg * D_E + ((c16 ^ (row & 7)) << 3);
                gload_lds16(src, (void*)&es[cur ^ 1][(size_t)c << 3]);
            }
        }

        const char* esb = reinterpret_cast<const char*>(&es[cur][0]);

        f32x4 acc[2][2];
        #pragma unroll
        for (int mf = 0; mf < 2; ++mf)
            #pragma unroll
            for (int nf = 0; nf < 2; ++nf)
                acc[mf][nf] = (f32x4){0.f, 0.f, 0.f, 0.f};

        __builtin_amdgcn_s_setprio(1);
        #pragma unroll
        for (int ks = 0; ks < 8; ++ks) {
            const int kb = ks * 64 + lk * 16;
            bf16x8 ef[2];
            #pragma unroll
            for (int nf = 0; nf < 2; ++nf) {
                const int row = wn + nf * 16 + l15;
                const int cb  = kb ^ ((row & 7) << 4);
                ef[nf] = *reinterpret_cast<const bf16x8*>(esb + row * 512 + cb);
            }
            #pragma unroll
            for (int mf = 0; mf < 2; ++mf) {
                const int rq  = wm + mf * 16 + l15;
                const int cbq = kb ^ ((rq & 7) << 4);
                const bf16x8 qf =
                    *reinterpret_cast<const bf16x8*>(qsb + rq * 512 + cbq);
                acc[mf][0] = __builtin_amdgcn_mfma_f32_16x16x32_bf16(
                    ef[0], qf, acc[mf][0], 0, 0, 0);
                acc[mf][1] = __builtin_amdgcn_mfma_f32_16x16x32_bf16(
                    ef[1], qf, acc[mf][1], 0, 0, 0);
            }
        }
        __builtin_amdgcn_s_setprio(0);

        // stores: issued now, drained during the NEXT tile's compute —
        // never inside a waitcnt(0) (the r8 bottleneck).
        #pragma unroll
        for (int mf = 0; mf < 2; ++mf) {
            const int m = m0 + wm + mf * 16 + l15;
            #pragma unroll
            for (int nf = 0; nf < 2; ++nf) {
                const int n = n0 + wn + nf * 16 + lk * 4;
                if (n < E_TOT)
                    *reinterpret_cast<f32x4*>(&out[(size_t)m * E_TOT + n]) =
                        acc[mf][nf];
            }
        }
    }
}

// ---------------------------------------------------------------------------
extern "C" void kernel_launch(void* const* d_in, const int* in_sizes, int n_in,
                              void* d_out, int out_size, void* d_ws, size_t ws_size,
                              hipStream_t stream) {
    const float* x  = (const float*)d_in[0];   // [4,128,768]
    const float* W  = (const float*)d_in[1];   // [256,768]
    const float* b  = (const float*)d_in[2];   // [256]
    const float* en = (const float*)d_in[3];   // [100000,256]
    float* out = (float*)d_out;                // [512,100000]

    unsigned short* qb = (unsigned short*)d_ws;                 // 256 KB
    unsigned short* eb = (unsigned short*)((char*)d_ws + (size_t)M_TOT * D_E * 2);

    fused_pp<<<PP_GRID, 512, 0, stream>>>(x, W, b, en, qb, eb); // 1627 blocks
    sim_kernel<<<SIM_GRID, 512, 0, stream>>>(eb, qb, out);      // 252 blocks
}

// Round 20
// 128.031 us; speedup vs baseline: 1.9836x; 1.0258x over previous
//
#include <hip/hip_runtime.h>
#include <hip/hip_bf16.h>

#define D_IN  768
#define D_E   256
#define M_TOT 512      // B*S
#define E_TOT 100000

typedef __attribute__((ext_vector_type(4))) float f32x4;
typedef __attribute__((ext_vector_type(8))) short bf16x8;

__device__ __forceinline__ unsigned short bf16bits(float f) {
    union { __hip_bfloat16 h; unsigned short u; } c;
    c.h = __float2bfloat16(f);
    return c.u;
}

__device__ __forceinline__ void gload_lds16(const void* g, void* l) {
    __builtin_amdgcn_global_load_lds(
        (const __attribute__((address_space(1))) void*)g,
        (__attribute__((address_space(3))) void*)l, 16, 0, 0);
}

// ---------------------------------------------------------------------------
// Fused prep+proj (r9, at BW floor — unchanged):
//   blocks [0,64):    proj  qb[m][e] = bf16(tanh(x@W^T+b)/||row||)
//   blocks [64,1627): prep  eb[n][k] = bf16(en[n][k]/||en[n]||)
// ---------------------------------------------------------------------------
#define PROJ_BLOCKS 64
#define PREP_BLOCKS 1563                 // 1563*64 = 100032 >= 100000
#define PP_GRID (PROJ_BLOCKS + PREP_BLOCKS)
#define PTM 8
#define PBK 64
#define PROUNDS (D_IN / PBK)             // 12

__global__ __launch_bounds__(512) void fused_pp(
    const float* __restrict__ x, const float* __restrict__ W,
    const float* __restrict__ b, const float* __restrict__ en,
    unsigned short* __restrict__ qb, unsigned short* __restrict__ eb)
{
    __shared__ float ws[D_E * (PBK + 1)];   // 65 KB (proj only)
    __shared__ float xs[PTM][PBK];
    __shared__ float red[PTM][4];
    __shared__ float qiv[PTM];

    const int t   = threadIdx.x;
    const int bid = blockIdx.x;

    if (bid >= PROJ_BLOCKS) {
        const int lane = t & 63;
        const int gw   = (bid - PROJ_BLOCKS) * 8 + (t >> 6);
        #pragma unroll 2
        for (int i = 0; i < 8; ++i) {
            const int row = gw * 8 + i;
            if (row >= E_TOT) break;
            const float4 v = *reinterpret_cast<const float4*>(
                en + (size_t)row * D_E + lane * 4);
            float s = v.x*v.x + v.y*v.y + v.z*v.z + v.w*v.w;
            #pragma unroll
            for (int off = 1; off < 64; off <<= 1) s += __shfl_xor(s, off, 64);
            const float sc = 1.0f / fmaxf(sqrtf(s), 1e-8f);
            union { unsigned short u[4]; uint2 d; } o;
            o.u[0] = bf16bits(v.x * sc); o.u[1] = bf16bits(v.y * sc);
            o.u[2] = bf16bits(v.z * sc); o.u[3] = bf16bits(v.w * sc);
            *reinterpret_cast<uint2*>(eb + (size_t)row * D_E + lane * 4) = o.d;
        }
        return;
    }

    const int m0   = bid * PTM;
    const int e    = t & 255;
    const int half = t >> 8;
    const int c4   = t & 15;
    const int rr   = t >> 4;

    float4 wreg[8];
    float  xreg = 0.f;
    float  acc[4] = {0.f, 0.f, 0.f, 0.f};

    #pragma unroll
    for (int i = 0; i < 8; ++i)
        wreg[i] = *reinterpret_cast<const float4*>(
            &W[(size_t)(i * 32 + rr) * D_IN + c4 * 4]);
    xreg = x[(size_t)(m0 + (t >> 6)) * D_IN + (t & 63)];

    for (int rd = 0; rd < PROUNDS; ++rd) {
        #pragma unroll
        for (int i = 0; i < 8; ++i) {
            float* dst = &ws[(i * 32 + rr) * (PBK + 1) + c4 * 4];
            dst[0] = wreg[i].x; dst[1] = wreg[i].y;
            dst[2] = wreg[i].z; dst[3] = wreg[i].w;
        }
        xs[t >> 6][t & 63] = xreg;
        __syncthreads();
        if (rd + 1 < PROUNDS) {
            const int k0 = (rd + 1) * PBK;
            #pragma unroll
            for (int i = 0; i < 8; ++i)
                wreg[i] = *reinterpret_cast<const float4*>(
                    &W[(size_t)(i * 32 + rr) * D_IN + k0 + c4 * 4]);
            xreg = x[(size_t)(m0 + (t >> 6)) * D_IN + k0 + (t & 63)];
        }
        #pragma unroll
        for (int k = 0; k < PBK; ++k) {
            const float wv = ws[e * (PBK + 1) + k];
            #pragma unroll
            for (int j = 0; j < 4; ++j)
                acc[j] = fmaf(xs[half * 4 + j][k], wv, acc[j]);
        }
        __syncthreads();
    }

    const float bias = b[e];
    const int wv4 = (t >> 6) & 3;
    const int lane = t & 63;
    float q[4];
    #pragma unroll
    for (int j = 0; j < 4; ++j) {
        q[j] = tanhf(acc[j] + bias);
        float s = q[j] * q[j];
        #pragma unroll
        for (int off = 1; off < 64; off <<= 1) s += __shfl_xor(s, off, 64);
        if (lane == 0) red[half * 4 + j][wv4] = s;
    }
    __syncthreads();
    if (t < PTM) {
        const float s = red[t][0] + red[t][1] + red[t][2] + red[t][3];
        qiv[t] = 1.0f / fmaxf(sqrtf(s), 1e-8f);
    }
    __syncthreads();
    #pragma unroll
    for (int j = 0; j < 4; ++j)
        qb[(size_t)(m0 + half * 4 + j) * D_E + e] =
            bf16bits(q[j] * qiv[half * 4 + j]);
}

// ---------------------------------------------------------------------------
// Kernel 2 (v19b): r10's compute core + q-in-regs + 64 KB LDS
//  -> 2 blocks/CU = TWO INDEPENDENT BARRIER DOMAINS per CU (phase stagger).
//   pool 64 KB: qs (prologue, 128x256 bf16) -> qf 64 VGPR -> es buffers
//   (pool+0 / pool+16384, selected by ternary — no LDS pointer array, which
//   failed to compile in r19).  Same swizzles, same ds_read/MFMA loop, same
//   exact vmcnt(4) ladder, same stores-last placement as r10 (131.3 best).
//   TPB=13, grid 504 = 126 ngrps x 4 m-groups, XCD-chunked.
// ---------------------------------------------------------------------------
#define BM 128
#define BN 64
#define TPB 13
#define NGRPN 126                       // 126*13*64 = 104832 >= 100000
#define SIM_GRID (NGRPN * 4)            // 504

__global__ __launch_bounds__(512, 4) void sim_kernel(
    const unsigned short* __restrict__ eb, const unsigned short* __restrict__ qb,
    float* __restrict__ out)
{
    __shared__ unsigned short pool[32768];   // 64 KB total

    const int t    = threadIdx.x;
    const int lane = t & 63;
    const int wid  = t >> 6;        // 0..7
    const int l15  = lane & 15;
    const int lk   = lane >> 4;     // 0..3
    const int wm   = (wid >> 1) * 32;   // 0,32,64,96
    const int wn   = (wid & 1) * 32;    // 0,32

    int vbid;
    {
        const int q = SIM_GRID >> 3, r = SIM_GRID & 7;   // 63, 0
        const int xcd = blockIdx.x & 7, rk = blockIdx.x >> 3;
        vbid = (xcd < r ? xcd * (q + 1) : r * (q + 1) + (xcd - r) * q) + rk;
    }
    const int mg    = vbid & 3;
    const int ngrp  = vbid >> 2;            // 0..125
    const int m0    = mg * BM;
    const int nbase = ngrp * (TPB * BN);    // ngrp * 832

    if (nbase >= E_TOT) return;             // idle tail groups (block-uniform)

    int nt = (E_TOT - nbase + BN - 1) / BN;
    if (nt > TPB) nt = TPB;

    // ---- prologue 1: stage q tile (128x256 bf16 = 64 KB) into pool ----
    #pragma unroll
    for (int i = 0; i < 8; ++i) {
        const int c   = i * 512 + t;        // 0..4095
        const int row = c >> 5;             // 0..127
        const int c16 = c & 31;
        gload_lds16(qb + (size_t)(m0 + row) * D_E + ((c16 ^ (row & 7)) << 3),
                    (void*)&pool[(size_t)c << 3]);
    }
    asm volatile("s_waitcnt vmcnt(0)" ::: "memory");
    __builtin_amdgcn_sched_barrier(0);
    __builtin_amdgcn_s_barrier();
    __builtin_amdgcn_sched_barrier(0);

    // ---- prologue 2: q panel -> registers (remat-proof: LDS source) ----
    const char* qsb = reinterpret_cast<const char*>(pool);
    bf16x8 qf[2][8];
    #pragma unroll
    for (int mf = 0; mf < 2; ++mf) {
        const int rq = wm + mf * 16 + l15;
        #pragma unroll
        for (int ks = 0; ks < 8; ++ks) {
            const int cb = (ks * 64 + lk * 16) ^ ((rq & 7) << 4);
            qf[mf][ks] = *reinterpret_cast<const bf16x8*>(qsb + rq * 512 + cb);
        }
    }
    asm volatile("s_waitcnt lgkmcnt(0)" ::: "memory");
    __builtin_amdgcn_sched_barrier(0);
    __builtin_amdgcn_s_barrier();           // pool now free for es buffers
    __builtin_amdgcn_sched_barrier(0);

    // ---- stage entity tile 0 into pool[0:16384) ----
    #pragma unroll
    for (int i = 0; i < 4; ++i) {
        const int c   = i * 512 + t;
        const int row = c >> 5;             // 0..63
        const int c16 = c & 31;
        int rg = nbase + row; if (rg >= E_TOT) rg = E_TOT - 1;
        gload_lds16(eb + (size_t)rg * D_E + ((c16 ^ (row & 7)) << 3),
                    (void*)&pool[(size_t)c << 3]);
    }

    for (int tt = 0; tt < nt; ++tt) {
        const int n0 = nbase + tt * BN;

        // exact ladder (r10): retire stage(tt); prev stores stay in flight
        if (tt == 0) asm volatile("s_waitcnt vmcnt(0)" ::: "memory");
        else         asm volatile("s_waitcnt vmcnt(4)" ::: "memory");
        __builtin_amdgcn_s_barrier();
        __builtin_amdgcn_sched_barrier(0);

        const int cur = tt & 1;
        unsigned short* escur = pool + (cur ? 16384 : 0);
        unsigned short* esnxt = pool + (cur ? 0 : 16384);

        if (tt + 1 < nt) {
            const int nn0 = n0 + BN;
            #pragma unroll
            for (int i = 0; i < 4; ++i) {
                const int c   = i * 512 + t;
                const int row = c >> 5;
                const int c16 = c & 31;
                int rg = nn0 + row; if (rg >= E_TOT) rg = E_TOT - 1;
                gload_lds16(eb + (size_t)rg * D_E + ((c16 ^ (row & 7)) << 3),
                            (void*)&esnxt[(size_t)c << 3]);
            }
        }

        const char* esb = reinterpret_cast<const char*>(escur);

        f32x4 acc[2][2];
        #pragma unroll
        for (int mf = 0; mf < 2; ++mf)
            #pragma unroll
            for (int nf = 0; nf < 2; ++nf)
                acc[mf][nf] = (f32x4){0.f, 0.f, 0.f, 0.f};

        __builtin_amdgcn_s_setprio(1);
        #pragma unroll
        for (int ks = 0; ks < 8; ++ks) {
            const int kb = ks * 64 + lk * 16;
            bf16x8 ef[2];
            #pragma unroll
            for (int nf = 0; nf < 2; ++nf) {
                const int row = wn + nf * 16 + l15;
                const int cb  = kb ^ ((row & 7) << 4);
                ef[nf] = *reinterpret_cast<const bf16x8*>(esb + row * 512 + cb);
            }
            #pragma unroll
            for (int mf = 0; mf < 2; ++mf) {
                acc[mf][0] = __builtin_amdgcn_mfma_f32_16x16x32_bf16(
                    ef[0], qf[mf][ks], acc[mf][0], 0, 0, 0);
                acc[mf][1] = __builtin_amdgcn_mfma_f32_16x16x32_bf16(
                    ef[1], qf[mf][ks], acc[mf][1], 0, 0, 0);
            }
        }
        __builtin_amdgcn_s_setprio(0);

        // stores last: drain during next tile's compute (never waited on)
        #pragma unroll
        for (int mf = 0; mf < 2; ++mf) {
            const int m = m0 + wm + mf * 16 + l15;
            #pragma unroll
            for (int nf = 0; nf < 2; ++nf) {
                const int n = n0 + wn + nf * 16 + lk * 4;
                if (n < E_TOT)
                    *reinterpret_cast<f32x4*>(&out[(size_t)m * E_TOT + n]) =
                        acc[mf][nf];
            }
        }
    }
}

// ---------------------------------------------------------------------------
extern "C" void kernel_launch(void* const* d_in, const int* in_sizes, int n_in,
                              void* d_out, int out_size, void* d_ws, size_t ws_size,
                              hipStream_t stream) {
    const float* x  = (const float*)d_in[0];   // [4,128,768]
    const float* W  = (const float*)d_in[1];   // [256,768]
    const float* b  = (const float*)d_in[2];   // [256]
    const float* en = (const float*)d_in[3];   // [100000,256]
    float* out = (float*)d_out;                // [512,100000]

    unsigned short* qb = (unsigned short*)d_ws;                 // 256 KB
    unsigned short* eb = (unsigned short*)((char*)d_ws + (size_t)M_TOT * D_E * 2);

    fused_pp<<<PP_GRID, 512, 0, stream>>>(x, W, b, en, qb, eb); // 1627 blocks
    sim_kernel<<<SIM_GRID, 512, 0, stream>>>(eb, qb, out);      // 504 blocks
}